// Round 1
// baseline (2191.745 us; speedup 1.0000x reference)
//
#include <hip/hip_runtime.h>
#include <stdint.h>

// MHA forward: B=4, L=2048, C=512, H=8, D=512 (HD=4096), TEMP=1, EPS=1e-5
// outputs: out0 = layernorm(ctx@Wo + bo + q)  [4,2048,512] fp32
//          atten = softmax(mask(qh@khT))      [32,2048,2048] fp32
//
// Precision strategy: hi/lo bf16 split (3 MFMAs) for Q/K projection and QK^T
// so attention probabilities are ~fp32-accurate; plain bf16 elsewhere.
// Workspace: 344 MB (ctx reuses qh region, xbuf reuses kh region).

typedef unsigned short u16;
typedef __attribute__((ext_vector_type(8))) short short8;
typedef __attribute__((ext_vector_type(8))) __bf16 bf16x8;
typedef __attribute__((ext_vector_type(4))) float f32x4;

#define OP_BF16  0
#define OP_BF16S 1
#define OP_F32   2
#define OP_F32S  3

#define EPI_SPLIT  0
#define EPI_VHT    1
#define EPI_SCORES 2
#define EPI_CTX    3
#define EPI_OUT    4

__device__ __forceinline__ u16 f2bf(float f) {
  union { float f; uint32_t u; } x; x.f = f;
  uint32_t u = x.u;
  return (u16)((u + 0x7fffu + ((u >> 16) & 1u)) >> 16);  // RNE
}
__device__ __forceinline__ float bf2f(u16 h) {
  union { uint32_t u; float f; } x; x.u = ((uint32_t)h) << 16;
  return x.f;
}

__device__ __forceinline__ f32x4 mfma16(short8 a, short8 b, f32x4 c) {
  return __builtin_amdgcn_mfma_f32_16x16x32_bf16(
      __builtin_bit_cast(bf16x8, a), __builtin_bit_cast(bf16x8, b), c, 0, 0, 0);
}

// ---- staging: bf16 tile 128x32 row-major via global_load_lds (width 16) ----
template<int ES>  // element size (2 only used here)
__device__ __forceinline__ void stage_tile(const char* gbase, size_t grow, char* lds, int tid) {
  constexpr int ROWB = 32 * ES;                 // bytes per tile row
  constexpr int CHUNKS = (128 * ROWB) / 1024;   // 1 KB per wave-call
  constexpr int PW = CHUNKS / 4;                // 4 waves
  const int lane = tid & 63, wave = tid >> 6;
#pragma unroll
  for (int c = 0; c < PW; ++c) {
    int chunk = wave * PW + c;
    int off = chunk * 1024 + lane * 16;
    int r = off / ROWB;
    int cb = off - r * ROWB;
    const char* g = gbase + (size_t)r * grow + cb;
    __builtin_amdgcn_global_load_lds(
        (__attribute__((address_space(1))) void*)g,
        (__attribute__((address_space(3))) void*)(lds + chunk * 1024),
        16, 0, 0);
  }
}

// ---- staging: fp32 tile 128x32 with row pad to 36 floats (bank-conflict-free) ----
#define F32_ROWF 36
__device__ __forceinline__ void stage_tile_f32pad(const char* gbase, size_t grow, char* lds, int tid) {
#pragma unroll
  for (int c = 0; c < 4; ++c) {
    int idx = c * 256 + tid;          // 1024 float4s total
    int row = idx >> 3, col4 = idx & 7;
    f32x4 v = *(const f32x4*)(gbase + (size_t)row * grow + col4 * 16);
    *(f32x4*)(lds + (size_t)row * (F32_ROWF * 4) + col4 * 16) = v;
  }
}

// ---- fragment load (A and B share layout: row = lane&15, k = quad*8+j) ----
template<int M>
__device__ __forceinline__ void load_frag(const char* lds, int row, int kq, short8& h, short8& l) {
  if constexpr (M == OP_BF16 || M == OP_BF16S) {
    size_t off = ((size_t)row * 32 + kq) * 2;
    h = *(const short8*)(lds + off);
    if constexpr (M == OP_BF16S) l = *(const short8*)(lds + 8192 + off);
  } else {
    size_t off = ((size_t)row * F32_ROWF + kq) * 4;
    f32x4 x0 = *(const f32x4*)(lds + off);
    f32x4 x1 = *(const f32x4*)(lds + off + 16);
#pragma unroll
    for (int j = 0; j < 4; ++j) {
      u16 h0 = f2bf(x0[j]); u16 h1 = f2bf(x1[j]);
      h[j] = (short)h0; h[j + 4] = (short)h1;
      if constexpr (M == OP_F32S) {
        l[j]     = (short)f2bf(x0[j] - bf2f(h0));
        l[j + 4] = (short)f2bf(x1[j] - bf2f(h1));
      }
    }
  }
}

// ---- generic 128x128 MFMA GEMM: C[m][n] = sum_k A[m][k]*B[n][k] (+epilogue) ----
template<int AM, int BM, int EPI>
__global__ __launch_bounds__(256, 2)
void gemm_k(const char* __restrict__ Ah, const char* __restrict__ Al,
            const char* __restrict__ Bh, const char* __restrict__ Bl,
            int lda, int ldb, int K,
            char* __restrict__ C0, char* __restrict__ C1,
            const int* __restrict__ mask, const float* __restrict__ bias,
            const float* __restrict__ resid) {
  constexpr int ASZ = (AM == OP_BF16) ? 8192 : (AM == OP_BF16S) ? 16384 : 128 * F32_ROWF * 4;
  constexpr int BSZ = (BM == OP_BF16) ? 8192 : (BM == OP_BF16S) ? 16384 : 128 * F32_ROWF * 4;
  __shared__ alignas(16) char smem[ASZ + BSZ];
  char* sA = smem;
  char* sB = smem + ASZ;

  const int tid = threadIdx.x, lane = tid & 63, wave = tid >> 6;
  const int wm = wave >> 1, wn = wave & 1;
  const int m0 = blockIdx.x * 128, n0 = blockIdx.y * 128;

  const char* pAh = Ah; const char* pAl = Al;
  const char* pBh = Bh; const char* pBl = Bl;
  if constexpr (EPI == EPI_SCORES) {
    int z = blockIdx.z, h = z >> 2, b = z & 3;
    size_t e2 = ((size_t)b * 2048 * 4096 + (size_t)h * 512) * 2;
    pAh += e2; pAl += e2; pBh += e2; pBl += e2;
  } else if constexpr (EPI == EPI_CTX) {
    int z = blockIdx.z, h = z >> 2, b = z & 3;
    pAh += ((size_t)z << 22) * 4;                       // atten block (fp32)
    pBh += ((size_t)(b * 8 + h) * 512 * 2048) * 2;      // vhT block (bf16)
  }

  f32x4 acc[4][4];
#pragma unroll
  for (int i = 0; i < 4; ++i)
#pragma unroll
    for (int j = 0; j < 4; ++j) acc[i][j] = (f32x4){0.f, 0.f, 0.f, 0.f};

  for (int k0 = 0; k0 < K; k0 += 32) {
    if constexpr (AM == OP_BF16 || AM == OP_BF16S) {
      stage_tile<2>(pAh + ((size_t)m0 * lda + k0) * 2, (size_t)lda * 2, sA, tid);
      if constexpr (AM == OP_BF16S)
        stage_tile<2>(pAl + ((size_t)m0 * lda + k0) * 2, (size_t)lda * 2, sA + 8192, tid);
    } else {
      stage_tile_f32pad(pAh + ((size_t)m0 * lda + k0) * 4, (size_t)lda * 4, sA, tid);
    }
    if constexpr (BM == OP_BF16 || BM == OP_BF16S) {
      stage_tile<2>(pBh + ((size_t)n0 * ldb + k0) * 2, (size_t)ldb * 2, sB, tid);
      if constexpr (BM == OP_BF16S)
        stage_tile<2>(pBl + ((size_t)n0 * ldb + k0) * 2, (size_t)ldb * 2, sB + 8192, tid);
    } else {
      stage_tile_f32pad(pBh + ((size_t)n0 * ldb + k0) * 4, (size_t)ldb * 4, sB, tid);
    }
    __syncthreads();

    const int kq = (lane >> 4) * 8, l15 = lane & 15;
    short8 ah[4], al[4], bh2[4], bl2[4];
#pragma unroll
    for (int mi = 0; mi < 4; ++mi)
      load_frag<AM>(sA, wm * 64 + mi * 16 + l15, kq, ah[mi], al[mi]);
#pragma unroll
    for (int ni = 0; ni < 4; ++ni)
      load_frag<BM>(sB, wn * 64 + ni * 16 + l15, kq, bh2[ni], bl2[ni]);

#pragma unroll
    for (int mi = 0; mi < 4; ++mi)
#pragma unroll
      for (int ni = 0; ni < 4; ++ni) {
        acc[mi][ni] = mfma16(ah[mi], bh2[ni], acc[mi][ni]);
        if constexpr (AM == OP_BF16S || AM == OP_F32S)
          acc[mi][ni] = mfma16(al[mi], bh2[ni], acc[mi][ni]);
        if constexpr (BM == OP_BF16S || BM == OP_F32S)
          acc[mi][ni] = mfma16(ah[mi], bl2[ni], acc[mi][ni]);
      }
    __syncthreads();
  }

  // epilogue: C/D layout col=lane&15, row=quad*4+reg (m89/m91-verified)
  const int l15 = lane & 15, quad = lane >> 4;
#pragma unroll
  for (int mi = 0; mi < 4; ++mi)
#pragma unroll
    for (int ni = 0; ni < 4; ++ni)
#pragma unroll
      for (int r = 0; r < 4; ++r) {
        int m = m0 + wm * 64 + mi * 16 + quad * 4 + r;
        int n = n0 + wn * 64 + ni * 16 + l15;
        float v = acc[mi][ni][r];
        if constexpr (EPI == EPI_SPLIT) {
          v += bias[n];
          u16 h = f2bf(v);
          u16 l = f2bf(v - bf2f(h));
          ((u16*)C0)[(size_t)m * 4096 + n] = h;
          ((u16*)C1)[(size_t)m * 4096 + n] = l;
        } else if constexpr (EPI == EPI_VHT) {
          v += bias[m];  // m is hd index
          int hh = m >> 9, d = m & 511, bb = n >> 11, ll = n & 2047;
          ((u16*)C0)[(((size_t)(bb * 8 + hh) * 512 + d) << 11) + ll] = f2bf(v);
        } else if constexpr (EPI == EPI_SCORES) {
          int z = blockIdx.z, bb = z & 3;
          int mv = mask[((size_t)bb << 22) + ((size_t)m << 11) + n];
          ((float*)C0)[((size_t)z << 22) + ((size_t)m << 11) + n] = mv ? -1e30f : v;
        } else if constexpr (EPI == EPI_CTX) {
          int z = blockIdx.z, hh = z >> 2, bb = z & 3;
          ((u16*)C0)[((size_t)(bb * 2048 + m) << 12) + hh * 512 + n] = f2bf(v);
        } else {  // EPI_OUT
          v += bias[n] + resid[((size_t)m << 9) + n];
          ((float*)C0)[((size_t)m << 9) + n] = v;
        }
      }
}

// ---- weight transpose + bf16 (+split) convert: out[c*rows+r] = in[r*cols+c] ----
__global__ __launch_bounds__(256)
void transpose_cvt_k(const float* __restrict__ in, u16* __restrict__ Th,
                     u16* __restrict__ Tl, int rows_in, int cols_in, int do_split) {
  int idx = blockIdx.x * 256 + threadIdx.x;
  int total = rows_in * cols_in;
  if (idx >= total) return;
  int c = idx / rows_in, r = idx - c * rows_in;
  float x = in[(size_t)r * cols_in + c];
  u16 h = f2bf(x);
  Th[idx] = h;
  if (do_split) Tl[idx] = f2bf(x - bf2f(h));
}

// ---- in-place row softmax over 2048 cols ----
__global__ __launch_bounds__(256)
void softmax_k(float* __restrict__ att) {
  __shared__ float sm[4];
  int t = threadIdx.x, lane = t & 63, wave = t >> 6;
  float4* row = (float4*)(att + ((size_t)blockIdx.x << 11));
  float4 a = row[t], b = row[t + 256];
  float mx = fmaxf(fmaxf(fmaxf(a.x, a.y), fmaxf(a.z, a.w)),
                   fmaxf(fmaxf(b.x, b.y), fmaxf(b.z, b.w)));
#pragma unroll
  for (int o = 32; o > 0; o >>= 1) mx = fmaxf(mx, __shfl_xor(mx, o));
  if (lane == 0) sm[wave] = mx;
  __syncthreads();
  mx = fmaxf(fmaxf(sm[0], sm[1]), fmaxf(sm[2], sm[3]));
  a.x = __expf(a.x - mx); a.y = __expf(a.y - mx);
  a.z = __expf(a.z - mx); a.w = __expf(a.w - mx);
  b.x = __expf(b.x - mx); b.y = __expf(b.y - mx);
  b.z = __expf(b.z - mx); b.w = __expf(b.w - mx);
  float s = a.x + a.y + a.z + a.w + b.x + b.y + b.z + b.w;
#pragma unroll
  for (int o = 32; o > 0; o >>= 1) s += __shfl_xor(s, o);
  __syncthreads();
  if (lane == 0) sm[wave] = s;
  __syncthreads();
  s = sm[0] + sm[1] + sm[2] + sm[3];
  float inv = 1.0f / s;
  a.x *= inv; a.y *= inv; a.z *= inv; a.w *= inv;
  b.x *= inv; b.y *= inv; b.z *= inv; b.w *= inv;
  row[t] = a; row[t + 256] = b;
}

// ---- layernorm over last dim (512), biased var, eps=1e-5 ----
__global__ __launch_bounds__(256)
void ln_k(const float* __restrict__ x, const float* __restrict__ gamma,
          const float* __restrict__ beta, float* __restrict__ out) {
  __shared__ float s1[4], s2[4];
  int t = threadIdx.x, lane = t & 63, wave = t >> 6;
  size_t base = (size_t)blockIdx.x << 9;
  float2 v = ((const float2*)(x + base))[t];
  float s = v.x + v.y;
  float q = v.x * v.x + v.y * v.y;
#pragma unroll
  for (int o = 32; o > 0; o >>= 1) { s += __shfl_xor(s, o); q += __shfl_xor(q, o); }
  if (lane == 0) { s1[wave] = s; s2[wave] = q; }
  __syncthreads();
  s = s1[0] + s1[1] + s1[2] + s1[3];
  q = s2[0] + s2[1] + s2[2] + s2[3];
  float mu = s * (1.0f / 512.0f);
  float var = q * (1.0f / 512.0f) - mu * mu;
  float rs = rsqrtf(var + 1e-5f);
  float2 g = ((const float2*)gamma)[t];
  float2 bb = ((const float2*)beta)[t];
  float2 o2;
  o2.x = (v.x - mu) * rs * g.x + bb.x;
  o2.y = (v.y - mu) * rs * g.y + bb.y;
  ((float2*)(out + base))[t] = o2;
}

extern "C" void kernel_launch(void* const* d_in, const int* in_sizes, int n_in,
                              void* d_out, int out_size, void* d_ws, size_t ws_size,
                              hipStream_t stream) {
  (void)in_sizes; (void)n_in; (void)out_size; (void)ws_size;
  const float* q     = (const float*)d_in[0];
  const float* k     = (const float*)d_in[1];
  const float* v     = (const float*)d_in[2];
  const int*   mask  = (const int*)d_in[3];
  const float* Wq    = (const float*)d_in[4];
  const float* bq    = (const float*)d_in[5];
  const float* Wk    = (const float*)d_in[6];
  const float* bk    = (const float*)d_in[7];
  const float* Wv    = (const float*)d_in[8];
  const float* bv    = (const float*)d_in[9];
  const float* Wo    = (const float*)d_in[10];
  const float* bo    = (const float*)d_in[11];
  const float* gamma = (const float*)d_in[12];
  const float* beta  = (const float*)d_in[13];

  float* out0  = (float*)d_out;
  float* atten = out0 + (size_t)4 * 2048 * 512;   // 4,194,304 offset

  char* ws = (char*)d_ws;
  const size_t MB = 1024ull * 1024ull;
  u16* qh_h = (u16*)(ws + 0 * MB);     // [8192x4096] bf16 hi
  u16* qh_l = (u16*)(ws + 64 * MB);
  u16* kh_h = (u16*)(ws + 128 * MB);
  u16* kh_l = (u16*)(ws + 192 * MB);
  u16* vhT  = (u16*)(ws + 256 * MB);   // [b][h][d][l] bf16
  u16* WqTh = (u16*)(ws + 320 * MB);   // [4096x512] bf16 hi
  u16* WqTl = (u16*)(ws + 324 * MB);
  u16* WkTh = (u16*)(ws + 328 * MB);
  u16* WkTl = (u16*)(ws + 332 * MB);
  u16* WvT  = (u16*)(ws + 336 * MB);
  u16* WoT  = (u16*)(ws + 340 * MB);   // [512x4096] bf16; ws end = 344 MB
  u16* ctx  = (u16*)(ws + 0 * MB);     // [8192x4096] bf16 — reuses dead qh region
  float* xbuf = (float*)(ws + 128 * MB); // [8192x512] fp32 — reuses dead kh region

  // weights: transpose to N x K, convert (split for Wq/Wk)
  transpose_cvt_k<<<8192, 256, 0, stream>>>(Wq, WqTh, WqTl, 512, 4096, 1);
  transpose_cvt_k<<<8192, 256, 0, stream>>>(Wk, WkTh, WkTl, 512, 4096, 1);
  transpose_cvt_k<<<8192, 256, 0, stream>>>(Wv, WvT, nullptr, 512, 4096, 0);
  transpose_cvt_k<<<8192, 256, 0, stream>>>(Wo, WoT, nullptr, 4096, 512, 0);

  // Q/K projections (split precision), outputs as bf16 hi/lo pairs
  gemm_k<OP_F32S, OP_BF16S, EPI_SPLIT><<<dim3(64, 32, 1), 256, 0, stream>>>(
      (const char*)q, nullptr, (const char*)WqTh, (const char*)WqTl,
      512, 512, 512, (char*)qh_h, (char*)qh_l, nullptr, bq, nullptr);
  gemm_k<OP_F32S, OP_BF16S, EPI_SPLIT><<<dim3(64, 32, 1), 256, 0, stream>>>(
      (const char*)k, nullptr, (const char*)WkTh, (const char*)WkTl,
      512, 512, 512, (char*)kh_h, (char*)kh_l, nullptr, bk, nullptr);

  // V projection, written directly transposed: vhT[b][h][d][l]
  gemm_k<OP_BF16, OP_F32, EPI_VHT><<<dim3(32, 64, 1), 256, 0, stream>>>(
      (const char*)WvT, nullptr, (const char*)v, nullptr,
      512, 512, 512, (char*)vhT, nullptr, nullptr, bv, nullptr);

  // scores = qh @ kh^T per (h,b), mask applied, raw scores -> d_out atten region
  gemm_k<OP_BF16S, OP_BF16S, EPI_SCORES><<<dim3(16, 16, 32), 256, 0, stream>>>(
      (const char*)qh_h, (const char*)qh_l, (const char*)kh_h, (const char*)kh_l,
      4096, 4096, 512, (char*)atten, nullptr, mask, nullptr, nullptr);

  // softmax in place on d_out (65536 rows x 2048)
  softmax_k<<<65536, 256, 0, stream>>>(atten);

  // ctx = atten @ vh per (h,b)
  gemm_k<OP_F32, OP_BF16, EPI_CTX><<<dim3(16, 4, 32), 256, 0, stream>>>(
      (const char*)atten, nullptr, (const char*)vhT, nullptr,
      2048, 2048, 2048, (char*)ctx, nullptr, nullptr, nullptr, nullptr);

  // out = ctx @ Wo + bo + residual(q) -> xbuf
  gemm_k<OP_BF16, OP_BF16, EPI_OUT><<<dim3(64, 4, 1), 256, 0, stream>>>(
      (const char*)ctx, nullptr, (const char*)WoT, nullptr,
      4096, 4096, 4096, (char*)xbuf, nullptr, nullptr, bo, q);

  // layernorm -> out0
  ln_k<<<8192, 256, 0, stream>>>(xbuf, gamma, beta, out0);
}

// Round 2
// 1631.010 us; speedup vs baseline: 1.3438x; 1.3438x over previous
//
#include <hip/hip_runtime.h>
#include <stdint.h>

// MHA forward: B=4, L=2048, C=512, H=8, D=512 (HD=4096), TEMP=1, EPS=1e-5
// outputs: out0 = layernorm(ctx@Wo + bo + q)  [4,2048,512] fp32
//          atten = softmax(mask(qh@khT))      [32,2048,2048] fp32
//
// Precision: pure fp16 (2^-12 rel err), single MFMA per tile everywhere.
// Score err max ~0.035 -> atten err ~0.01 << 0.1 threshold.
// Mask: pre-converted to int8 (L3-resident), applied in softmax pass.
// Workspace peak: 288 MB.

typedef unsigned short u16;
typedef _Float16 f16;
typedef __attribute__((ext_vector_type(8))) _Float16 f16x8;
typedef __attribute__((ext_vector_type(4))) float f32x4;

#define OP_F16 0
#define OP_F32 1

#define EPI_QKH    0
#define EPI_VHT    1
#define EPI_SCORES 2
#define EPI_CTX    3
#define EPI_OUT    4

__device__ __forceinline__ f32x4 mfma16(f16x8 a, f16x8 b, f32x4 c) {
  return __builtin_amdgcn_mfma_f32_16x16x32_f16(a, b, c, 0, 0, 0);
}

// ---- staging: f16 tile 128x32 row-major via global_load_lds (width 16) ----
__device__ __forceinline__ void stage_tile_f16(const char* gbase, size_t grow, char* lds, int tid) {
  const int lane = tid & 63, wave = tid >> 6;
#pragma unroll
  for (int c = 0; c < 2; ++c) {            // 8 KB tile = 8 chunks of 1 KB, 2/wave
    int chunk = wave * 2 + c;
    int off = chunk * 1024 + lane * 16;    // 64 B per row
    int r = off >> 6;
    int cb = off & 63;
    const char* g = gbase + (size_t)r * grow + cb;
    __builtin_amdgcn_global_load_lds(
        (__attribute__((address_space(1))) void*)g,
        (__attribute__((address_space(3))) void*)(lds + chunk * 1024),
        16, 0, 0);
  }
}

// ---- staging: fp32 tile 128x32 with row pad to 36 floats ----
#define F32_ROWF 36
__device__ __forceinline__ void stage_tile_f32pad(const char* gbase, size_t grow, char* lds, int tid) {
#pragma unroll
  for (int c = 0; c < 4; ++c) {
    int idx = c * 256 + tid;          // 1024 float4s total
    int row = idx >> 3, col4 = idx & 7;
    f32x4 v = *(const f32x4*)(gbase + (size_t)row * grow + col4 * 16);
    *(f32x4*)(lds + (size_t)row * (F32_ROWF * 4) + col4 * 16) = v;
  }
}

// ---- fragment load (A and B share layout: row = lane&15, k = quad*8+j) ----
template<int M>
__device__ __forceinline__ f16x8 load_frag(const char* lds, int row, int kq) {
  if constexpr (M == OP_F16) {
    return *(const f16x8*)(lds + ((size_t)row * 32 + kq) * 2);
  } else {
    size_t off = ((size_t)row * F32_ROWF + kq) * 4;
    f32x4 x0 = *(const f32x4*)(lds + off);
    f32x4 x1 = *(const f32x4*)(lds + off + 16);
    f16x8 h;
#pragma unroll
    for (int j = 0; j < 4; ++j) {
      h[j]     = (_Float16)x0[j];
      h[j + 4] = (_Float16)x1[j];
    }
    return h;
  }
}

// ---- generic 128x128 MFMA GEMM: C[m][n] = sum_k A[m][k]*B[n][k] (+epilogue) ----
template<int AM, int BM, int EPI>
__global__ __launch_bounds__(256, 2)
void gemm_k(const char* __restrict__ A, const char* __restrict__ B,
            int lda, int ldb, int K,
            char* __restrict__ C0,
            const float* __restrict__ bias, const float* __restrict__ resid) {
  constexpr int ASZ = (AM == OP_F16) ? 8192 : 128 * F32_ROWF * 4;
  constexpr int BSZ = (BM == OP_F16) ? 8192 : 128 * F32_ROWF * 4;
  __shared__ alignas(16) char smem[ASZ + BSZ];
  char* sA = smem;
  char* sB = smem + ASZ;

  const int tid = threadIdx.x, lane = tid & 63, wave = tid >> 6;
  const int wm = wave >> 1, wn = wave & 1;
  const int m0 = blockIdx.x * 128, n0 = blockIdx.y * 128;

  const char* pA = A; const char* pB = B;
  if constexpr (EPI == EPI_SCORES) {
    int z = blockIdx.z, h = z >> 2, b = z & 3;
    size_t e2 = ((size_t)b * 2048 * 4096 + (size_t)h * 512) * 2;
    pA += e2; pB += e2;
  } else if constexpr (EPI == EPI_CTX) {
    int z = blockIdx.z, h = z >> 2, b = z & 3;
    pA += ((size_t)z << 22) * 4;                       // atten block (fp32)
    pB += ((size_t)(b * 8 + h) * 512 * 2048) * 2;      // vhT block (f16)
  }

  f32x4 acc[4][4];
#pragma unroll
  for (int i = 0; i < 4; ++i)
#pragma unroll
    for (int j = 0; j < 4; ++j) acc[i][j] = (f32x4){0.f, 0.f, 0.f, 0.f};

  for (int k0 = 0; k0 < K; k0 += 32) {
    if constexpr (AM == OP_F16)
      stage_tile_f16(pA + ((size_t)m0 * lda + k0) * 2, (size_t)lda * 2, sA, tid);
    else
      stage_tile_f32pad(pA + ((size_t)m0 * lda + k0) * 4, (size_t)lda * 4, sA, tid);
    if constexpr (BM == OP_F16)
      stage_tile_f16(pB + ((size_t)n0 * ldb + k0) * 2, (size_t)ldb * 2, sB, tid);
    else
      stage_tile_f32pad(pB + ((size_t)n0 * ldb + k0) * 4, (size_t)ldb * 4, sB, tid);
    __syncthreads();

    const int kq = (lane >> 4) * 8, l15 = lane & 15;
    f16x8 af[4], bf[4];
#pragma unroll
    for (int mi = 0; mi < 4; ++mi)
      af[mi] = load_frag<AM>(sA, wm * 64 + mi * 16 + l15, kq);
#pragma unroll
    for (int ni = 0; ni < 4; ++ni)
      bf[ni] = load_frag<BM>(sB, wn * 64 + ni * 16 + l15, kq);

#pragma unroll
    for (int mi = 0; mi < 4; ++mi)
#pragma unroll
      for (int ni = 0; ni < 4; ++ni)
        acc[mi][ni] = mfma16(af[mi], bf[ni], acc[mi][ni]);
    __syncthreads();
  }

  // epilogue: C/D layout col=lane&15, row=quad*4+reg (m89/m91-verified)
  const int l15 = lane & 15, quad = lane >> 4;
#pragma unroll
  for (int mi = 0; mi < 4; ++mi)
#pragma unroll
    for (int ni = 0; ni < 4; ++ni)
#pragma unroll
      for (int r = 0; r < 4; ++r) {
        int m = m0 + wm * 64 + mi * 16 + quad * 4 + r;
        int n = n0 + wn * 64 + ni * 16 + l15;
        float v = acc[mi][ni][r];
        if constexpr (EPI == EPI_QKH) {
          v += bias[n];
          ((f16*)C0)[(size_t)m * 4096 + n] = (f16)v;
        } else if constexpr (EPI == EPI_VHT) {
          v += bias[m];  // m is hd index
          int hh = m >> 9, d = m & 511, bb = n >> 11, ll = n & 2047;
          ((f16*)C0)[(((size_t)(bb * 8 + hh) * 512 + d) << 11) + ll] = (f16)v;
        } else if constexpr (EPI == EPI_SCORES) {
          int z = blockIdx.z;
          ((float*)C0)[((size_t)z << 22) + ((size_t)m << 11) + n] = v;
        } else if constexpr (EPI == EPI_CTX) {
          int z = blockIdx.z, hh = z >> 2, bb = z & 3;
          ((f16*)C0)[((size_t)(bb * 2048 + m) << 12) + hh * 512 + n] = (f16)v;
        } else {  // EPI_OUT
          v += bias[n] + resid[((size_t)m << 9) + n];
          ((float*)C0)[((size_t)m << 9) + n] = v;
        }
      }
}

// ---- weight transpose + f16 convert: out[c*rows+r] = in[r*cols+c] ----
__global__ __launch_bounds__(256)
void transpose_cvt_k(const float* __restrict__ in, f16* __restrict__ T,
                     int rows_in, int cols_in) {
  int idx = blockIdx.x * 256 + threadIdx.x;
  if (idx >= rows_in * cols_in) return;
  int c = idx / rows_in, r = idx - c * rows_in;
  T[idx] = (f16)in[(size_t)r * cols_in + c];
}

// ---- mask int32 -> int8 ----
__global__ __launch_bounds__(256)
void maskprep_k(const int* __restrict__ m32, unsigned char* __restrict__ m8) {
  int i = blockIdx.x * 256 + threadIdx.x;   // 4,194,304 int4s
  int4 v = ((const int4*)m32)[i];
  uchar4 c;
  c.x = (unsigned char)v.x; c.y = (unsigned char)v.y;
  c.z = (unsigned char)v.z; c.w = (unsigned char)v.w;
  ((uchar4*)m8)[i] = c;
}

// ---- masked in-place row softmax over 2048 cols ----
__global__ __launch_bounds__(256)
void softmax_k(float* __restrict__ att, const unsigned char* __restrict__ m8) {
  __shared__ float sm[4];
  int t = threadIdx.x, lane = t & 63, wave = t >> 6;
  size_t r = blockIdx.x;
  int z = (int)(r >> 11), m = (int)(r & 2047), b = z & 3;
  float4* row = (float4*)(att + (r << 11));
  const uchar4* mrow = (const uchar4*)(m8 + (((size_t)b << 22) + ((size_t)m << 11)));
  float4 a = row[t], c = row[t + 256];
  uchar4 ma = mrow[t], mc = mrow[t + 256];
  if (ma.x) a.x = -1e30f; if (ma.y) a.y = -1e30f;
  if (ma.z) a.z = -1e30f; if (ma.w) a.w = -1e30f;
  if (mc.x) c.x = -1e30f; if (mc.y) c.y = -1e30f;
  if (mc.z) c.z = -1e30f; if (mc.w) c.w = -1e30f;
  float mx = fmaxf(fmaxf(fmaxf(a.x, a.y), fmaxf(a.z, a.w)),
                   fmaxf(fmaxf(c.x, c.y), fmaxf(c.z, c.w)));
#pragma unroll
  for (int o = 32; o > 0; o >>= 1) mx = fmaxf(mx, __shfl_xor(mx, o));
  if (lane == 0) sm[wave] = mx;
  __syncthreads();
  mx = fmaxf(fmaxf(sm[0], sm[1]), fmaxf(sm[2], sm[3]));
  a.x = __expf(a.x - mx); a.y = __expf(a.y - mx);
  a.z = __expf(a.z - mx); a.w = __expf(a.w - mx);
  c.x = __expf(c.x - mx); c.y = __expf(c.y - mx);
  c.z = __expf(c.z - mx); c.w = __expf(c.w - mx);
  float s = a.x + a.y + a.z + a.w + c.x + c.y + c.z + c.w;
#pragma unroll
  for (int o = 32; o > 0; o >>= 1) s += __shfl_xor(s, o);
  __syncthreads();
  if (lane == 0) sm[wave] = s;
  __syncthreads();
  s = sm[0] + sm[1] + sm[2] + sm[3];
  float inv = 1.0f / s;
  a.x *= inv; a.y *= inv; a.z *= inv; a.w *= inv;
  c.x *= inv; c.y *= inv; c.z *= inv; c.w *= inv;
  row[t] = a; row[t + 256] = c;
}

// ---- layernorm over last dim (512), biased var, eps=1e-5 ----
__global__ __launch_bounds__(256)
void ln_k(const float* __restrict__ x, const float* __restrict__ gamma,
          const float* __restrict__ beta, float* __restrict__ out) {
  __shared__ float s1[4], s2[4];
  int t = threadIdx.x, lane = t & 63, wave = t >> 6;
  size_t base = (size_t)blockIdx.x << 9;
  float2 v = ((const float2*)(x + base))[t];
  float s = v.x + v.y;
  float q = v.x * v.x + v.y * v.y;
#pragma unroll
  for (int o = 32; o > 0; o >>= 1) { s += __shfl_xor(s, o); q += __shfl_xor(q, o); }
  if (lane == 0) { s1[wave] = s; s2[wave] = q; }
  __syncthreads();
  s = s1[0] + s1[1] + s1[2] + s1[3];
  q = s2[0] + s2[1] + s2[2] + s2[3];
  float mu = s * (1.0f / 512.0f);
  float var = q * (1.0f / 512.0f) - mu * mu;
  float rs = rsqrtf(var + 1e-5f);
  float2 g = ((const float2*)gamma)[t];
  float2 bb = ((const float2*)beta)[t];
  float2 o2;
  o2.x = (v.x - mu) * rs * g.x + bb.x;
  o2.y = (v.y - mu) * rs * g.y + bb.y;
  ((float2*)(out + base))[t] = o2;
}

extern "C" void kernel_launch(void* const* d_in, const int* in_sizes, int n_in,
                              void* d_out, int out_size, void* d_ws, size_t ws_size,
                              hipStream_t stream) {
  (void)in_sizes; (void)n_in; (void)out_size; (void)ws_size;
  const float* q     = (const float*)d_in[0];
  const float* k     = (const float*)d_in[1];
  const float* v     = (const float*)d_in[2];
  const int*   mask  = (const int*)d_in[3];
  const float* Wq    = (const float*)d_in[4];
  const float* bq    = (const float*)d_in[5];
  const float* Wk    = (const float*)d_in[6];
  const float* bk    = (const float*)d_in[7];
  const float* Wv    = (const float*)d_in[8];
  const float* bv    = (const float*)d_in[9];
  const float* Wo    = (const float*)d_in[10];
  const float* bo    = (const float*)d_in[11];
  const float* gamma = (const float*)d_in[12];
  const float* beta  = (const float*)d_in[13];

  float* out0  = (float*)d_out;
  float* atten = out0 + (size_t)4 * 2048 * 512;

  char* ws = (char*)d_ws;
  const size_t MB = 1024ull * 1024ull;
  f16* WqT  = (f16*)(ws + 0 * MB);     // [4096x512]
  f16* WkT  = (f16*)(ws + 4 * MB);
  f16* WvT  = (f16*)(ws + 8 * MB);
  f16* WoT  = (f16*)(ws + 12 * MB);    // [512x4096]
  unsigned char* mask8 = (unsigned char*)(ws + 16 * MB);  // 16 MB
  f16* vhT  = (f16*)(ws + 32 * MB);    // [b][h][d][l] = 64 MB
  f16* qh   = (f16*)(ws + 96 * MB);    // [8192x4096] = 64 MB
  f16* kh   = (f16*)(ws + 160 * MB);   // 64 MB
  f16* ctx  = (f16*)(ws + 224 * MB);   // [8192x4096] = 64 MB, ends 288 MB
  float* xbuf = (float*)(ws + 96 * MB);  // reuses dead qh (16 MB fp32)

  // prep: weight transposes to NxK f16, mask to int8
  transpose_cvt_k<<<8192, 256, 0, stream>>>(Wq, WqT, 512, 4096);
  transpose_cvt_k<<<8192, 256, 0, stream>>>(Wk, WkT, 512, 4096);
  transpose_cvt_k<<<8192, 256, 0, stream>>>(Wv, WvT, 512, 4096);
  transpose_cvt_k<<<8192, 256, 0, stream>>>(Wo, WoT, 4096, 512);
  maskprep_k<<<16384, 256, 0, stream>>>(mask, mask8);

  // Q/K projections -> f16
  gemm_k<OP_F32, OP_F16, EPI_QKH><<<dim3(64, 32, 1), 256, 0, stream>>>(
      (const char*)q, (const char*)WqT, 512, 512, 512, (char*)qh, bq, nullptr);
  gemm_k<OP_F32, OP_F16, EPI_QKH><<<dim3(64, 32, 1), 256, 0, stream>>>(
      (const char*)k, (const char*)WkT, 512, 512, 512, (char*)kh, bk, nullptr);

  // V projection, written directly transposed: vhT[b][h][d][l]
  gemm_k<OP_F16, OP_F32, EPI_VHT><<<dim3(32, 64, 1), 256, 0, stream>>>(
      (const char*)WvT, (const char*)v, 512, 512, 512, (char*)vhT, bv, nullptr);

  // raw scores = qh @ kh^T per (h,b) -> d_out atten region
  gemm_k<OP_F16, OP_F16, EPI_SCORES><<<dim3(16, 16, 32), 256, 0, stream>>>(
      (const char*)qh, (const char*)kh, 4096, 4096, 512, (char*)atten, nullptr, nullptr);

  // masked softmax in place on d_out (65536 rows x 2048)
  softmax_k<<<65536, 256, 0, stream>>>(atten, mask8);

  // ctx = atten @ vh per (h,b)
  gemm_k<OP_F32, OP_F16, EPI_CTX><<<dim3(16, 4, 32), 256, 0, stream>>>(
      (const char*)atten, (const char*)vhT, 2048, 2048, 2048, (char*)ctx, nullptr, nullptr);

  // out = ctx @ Wo + bo + residual(q) -> xbuf
  gemm_k<OP_F16, OP_F16, EPI_OUT><<<dim3(64, 4, 1), 256, 0, stream>>>(
      (const char*)ctx, (const char*)WoT, 4096, 4096, 4096, (char*)xbuf, bo, q);

  // layernorm -> out0
  ln_k<<<8192, 256, 0, stream>>>(xbuf, gamma, beta, out0);
}